// Round 1
// baseline (236.714 us; speedup 1.0000x reference)
//
#include <hip/hip_runtime.h>

// UniformBottomUpHTMM: T=64 trees, depth 10 (N1=2047 heap layout), C=16,
// M=64, G=16. r12: BARRIER-FREE restructure. Previous version staged
// symbols+params in d_ws behind a device-wide atomic-RMW barrier; rocprof
// showed 81 MB WRITE_SIZE / 42 MB FETCH (vs ~1.2 MB problem footprint) and
// VALUBusy 15% -- the coherent-point RMW polling was both a memory storm
// and a full-device serialization. Every block is now self-sufficient:
//   - loads its own tree's 2047 symbols (coalesced, L2-resident),
//   - recomputes the softmax of its g's params into LDS (~1.3K floats),
//   - runs the bottom-up pass for ONE (t,g) pair.
// 1024 independent blocks (64 t x 16 g), no workspace, no atomics, no rep
// loop. Without the co-residency constraint we raise occupancy to
// 4 blocks/CU (LDS 31.5KB*4=126KB<160KB, VGPR budget 128 = prior usage).

#define C_DIM 16
#define M_DIM 64
#define G_DIM 16
#define T_TREES 64
#define N1 2047
#define NBLOCKS (T_TREES * G_DIM)   // 1024

__global__ __launch_bounds__(256, 4) void htmm_fused(
    const int* __restrict__ x,
    const int* __restrict__ inv_map,
    const float* __restrict__ lA,
    const float* __restrict__ lB,
    const float* __restrict__ lPi,
    float* __restrict__ out)
{
    const int bid = blockIdx.x;           // 1024 blocks: g = bid>>6, t = bid&63
    const int tid = threadIdx.x;
    const int g = bid >> 6;
    const int t = bid & (T_TREES - 1);    // bid%8 == t%8 -> 16 same-tree blocks share an XCD L2

    __shared__ __align__(16) float sA[C_DIM * C_DIM];
    __shared__ __align__(16) float sB[C_DIM * M_DIM];
    __shared__ __align__(16) float sPi[C_DIM];
    __shared__ __align__(16) unsigned char xs[2048];
    __shared__ float buf0[C_DIM * 256];   // L8 betas (SoA stride 256)
    __shared__ float buf1[C_DIM * 128];
    __shared__ float wsum[4];

    // ---- per-block staging: tree symbols (coalesced; identity inv_map in
    // practice -> both loads coalesced, and 16 blocks/tree hit L2) ----
    {
        const int base = t * N1;
        for (int i = tid; i < N1; i += 256)
            xs[i] = (unsigned char)x[inv_map[base + i]];
    }
    // ---- per-block param softmax for this g (replaces ws staging) ----
    {   // A: softmax over i (axis 0) within 16-lane segments; one (i,j)/thread
        int j = tid >> 4, i = tid & 15;
        float v = lA[(i * C_DIM + j) * G_DIM + g];
        float mx = v;
        #pragma unroll
        for (int m = 1; m < 16; m <<= 1) mx = fmaxf(mx, __shfl_xor(mx, m, 16));
        float e = __expf(v - mx);
        float s = e;
        #pragma unroll
        for (int m = 1; m < 16; m <<= 1) s += __shfl_xor(s, m, 16);
        sA[i * C_DIM + j] = e / s;
    }
    {   // B: softmax over m (axis 1), row c, 4 symbols per lane
        int c = tid >> 4, l16 = tid & 15;
        float e0 = lB[(c * M_DIM + l16 +  0) * G_DIM + g];
        float e1 = lB[(c * M_DIM + l16 + 16) * G_DIM + g];
        float e2 = lB[(c * M_DIM + l16 + 32) * G_DIM + g];
        float e3 = lB[(c * M_DIM + l16 + 48) * G_DIM + g];
        float mx = fmaxf(fmaxf(e0, e1), fmaxf(e2, e3));
        #pragma unroll
        for (int m = 1; m < 16; m <<= 1) mx = fmaxf(mx, __shfl_xor(mx, m, 16));
        e0 = __expf(e0 - mx); e1 = __expf(e1 - mx);
        e2 = __expf(e2 - mx); e3 = __expf(e3 - mx);
        float s = e0 + e1 + e2 + e3;
        #pragma unroll
        for (int m = 1; m < 16; m <<= 1) s += __shfl_xor(s, m, 16);
        float inv = 1.f / s;
        sB[c * M_DIM + l16 +  0] = e0 * inv;
        sB[c * M_DIM + l16 + 16] = e1 * inv;
        sB[c * M_DIM + l16 + 32] = e2 * inv;
        sB[c * M_DIM + l16 + 48] = e3 * inv;
    }
    if (tid < C_DIM) {  // Pi: softmax over c across lanes 0..15
        float v = lPi[tid * G_DIM + g];
        float mx = v;
        #pragma unroll
        for (int m = 1; m < 16; m <<= 1) mx = fmaxf(mx, __shfl_xor(mx, m, 16));
        float e = __expf(v - mx);
        float s = e;
        #pragma unroll
        for (int m = 1; m < 16; m <<= 1) s += __shfl_xor(s, m, 16);
        sPi[tid] = e / s;
    }
    __syncthreads();

    float ll = 0.f;

    // ---- fused leaves (L10) + L9 + L8: one L8 node per thread ----
    {
        const int idx = tid;
        const int p8  = 255 + idx;
        float s8[C_DIM];
        #pragma unroll
        for (int k = 0; k < C_DIM; ++k) s8[k] = 0.f;
        #pragma unroll
        for (int c9 = 0; c9 < 2; ++c9) {
            const int p9 = 2 * p8 + 1 + c9;
            float s9[C_DIM];
            #pragma unroll
            for (int k = 0; k < C_DIM; ++k) s9[k] = 0.f;
            #pragma unroll
            for (int cl = 0; cl < 2; ++cl) {
                const int xv = xs[2 * p9 + 1 + cl];
                float b[C_DIM]; float nu = 0.f;
                #pragma unroll
                for (int k = 0; k < C_DIM; ++k) {
                    b[k] = sPi[k] * sB[k * M_DIM + xv];
                    nu += b[k];
                }
                float inv = 0.5f / nu;
                #pragma unroll
                for (int k = 0; k < C_DIM; ++k) s9[k] += b[k] * inv;
                ll += __logf(nu);
            }
            const int xv = xs[p9];
            float bp[C_DIM]; float nu = 0.f;
            #pragma unroll
            for (int i = 0; i < C_DIM; ++i) {
                float ti = 0.f;
                #pragma unroll
                for (int j = 0; j < C_DIM; ++j) ti += sA[i * C_DIM + j] * s9[j];
                bp[i] = ti * sB[i * M_DIM + xv];
                nu += bp[i];
            }
            ll += __logf(nu);
            float inv = 0.5f / nu;
            #pragma unroll
            for (int k = 0; k < C_DIM; ++k) s8[k] += bp[k] * inv;
        }
        const int xv = xs[p8];
        float bp[C_DIM]; float nu = 0.f;
        #pragma unroll
        for (int i = 0; i < C_DIM; ++i) {
            float ti = 0.f;
            #pragma unroll
            for (int j = 0; j < C_DIM; ++j) ti += sA[i * C_DIM + j] * s8[j];
            bp[i] = ti * sB[i * M_DIM + xv];
            nu += bp[i];
        }
        ll += __logf(nu);
        float inv = 1.f / nu;
        #pragma unroll
        for (int k = 0; k < C_DIM; ++k) buf0[k * 256 + idx] = bp[k] * inv;
    }
    __syncthreads();

    // ---- L7: 128 nodes ----
    if (tid < 128) {
        const int idx = tid;
        float s[C_DIM];
        #pragma unroll
        for (int j = 0; j < C_DIM; ++j) {
            float2 cv = ((const float2*)(buf0 + j * 256))[idx];
            s[j] = 0.5f * (cv.x + cv.y);
        }
        const int xv = xs[127 + idx];
        float bp[C_DIM]; float nu = 0.f;
        #pragma unroll
        for (int i = 0; i < C_DIM; ++i) {
            float ti = 0.f;
            #pragma unroll
            for (int j = 0; j < C_DIM; ++j) ti += sA[i * C_DIM + j] * s[j];
            bp[i] = ti * sB[i * M_DIM + xv];
            nu += bp[i];
        }
        ll += __logf(nu);
        float inv = 1.f / nu;
        #pragma unroll
        for (int i = 0; i < C_DIM; ++i) buf1[i * 128 + idx] = bp[i] * inv;
    }
    __syncthreads();

    // ---- L6..L0 (64..1 nodes): wave 0 only, LDS fences not barriers ----
    if (tid < 64) {
        float* cur = buf1; int cs = 128;
        float* nxt = buf0; int ns = 256;
        for (int cnt2 = 64; cnt2 >= 1; cnt2 >>= 1) {
            if (tid < cnt2) {
                const int idx = tid;
                float s[C_DIM];
                #pragma unroll
                for (int j = 0; j < C_DIM; ++j) {
                    float a  = cur[j * cs + 2 * idx];
                    float b2 = cur[j * cs + 2 * idx + 1];
                    s[j] = 0.5f * (a + b2);
                }
                const int xv = xs[cnt2 - 1 + idx];
                float bp[C_DIM]; float nu = 0.f;
                #pragma unroll
                for (int i = 0; i < C_DIM; ++i) {
                    float ti = 0.f;
                    #pragma unroll
                    for (int j = 0; j < C_DIM; ++j) ti += sA[i * C_DIM + j] * s[j];
                    bp[i] = ti * sB[i * M_DIM + xv];
                    nu += bp[i];
                }
                ll += __logf(nu);
                float inv = 1.f / nu;
                #pragma unroll
                for (int i = 0; i < C_DIM; ++i) nxt[i * ns + idx] = bp[i] * inv;
            }
            asm volatile("s_waitcnt lgkmcnt(0)" ::: "memory");
            __builtin_amdgcn_wave_barrier();
            float* tp = cur; cur = nxt; nxt = tp;
            int ts = cs; cs = ns; ns = ts;
        }
    }

    // ---- reduce ll across block ----
    float v = ll;
    #pragma unroll
    for (int off = 32; off > 0; off >>= 1) v += __shfl_down(v, off, 64);
    if ((tid & 63) == 0) wsum[tid >> 6] = v;
    __syncthreads();
    if (tid == 0) out[t * G_DIM + g] = wsum[0] + wsum[1] + wsum[2] + wsum[3];
}

extern "C" void kernel_launch(void* const* d_in, const int* in_sizes, int n_in,
                              void* d_out, int out_size, void* d_ws, size_t ws_size,
                              hipStream_t stream) {
    const int*   x       = (const int*)d_in[0];
    const int*   inv_map = (const int*)d_in[6];
    const float* lA      = (const float*)d_in[7];
    const float* lB      = (const float*)d_in[8];
    const float* lPi     = (const float*)d_in[9];
    float* out = (float*)d_out;

    htmm_fused<<<dim3(NBLOCKS), dim3(256), 0, stream>>>(
        x, inv_map, lA, lB, lPi, out);
}

// Round 2
// 149.909 us; speedup vs baseline: 1.5790x; 1.5790x over previous
//
#include <hip/hip_runtime.h>

// UniformBottomUpHTMM: T=64 trees, depth 10 (N1=2047 heap layout), C=16,
// M=64, G=16. r13: barrier-free structure from r12, with the register
// budget restored. r12's __launch_bounds__(256,4) made the compiler cap
// VGPRs at 64 (empirically the min-waves arg maps to a ~256/w cap here:
// w=2 -> 128, w=4 -> 64); the per-thread 16-float beta arrays spilled and
// rocprof showed 304 MB scratch WRITE_SIZE. Reverting to (256,2) restores
// the proven VGPR=128 / zero-spill codegen; launch bounds only guarantee a
// MINIMUM occupancy, so with 128 VGPRs (4 waves/SIMD) and 31.5 KB LDS
// (5 blocks/CU) the hardware still co-schedules 4 blocks/CU.
// Structure: 1024 independent blocks (one per (t,g)), no workspace, no
// atomics, no device barrier. Each block gathers its tree's 2047 symbols
// (L2-resident, 16 blocks/tree share them) and recomputes its g's softmax
// params into LDS, then runs the bottom-up pass.

#define C_DIM 16
#define M_DIM 64
#define G_DIM 16
#define T_TREES 64
#define N1 2047
#define NBLOCKS (T_TREES * G_DIM)   // 1024

__global__ __launch_bounds__(256, 2) void htmm_fused(
    const int* __restrict__ x,
    const int* __restrict__ inv_map,
    const float* __restrict__ lA,
    const float* __restrict__ lB,
    const float* __restrict__ lPi,
    float* __restrict__ out)
{
    const int bid = blockIdx.x;           // 1024 blocks: g = bid>>6, t = bid&63
    const int tid = threadIdx.x;
    const int g = bid >> 6;
    const int t = bid & (T_TREES - 1);    // bid%8 == t%8 -> 16 same-tree blocks share an XCD L2

    __shared__ __align__(16) float sA[C_DIM * C_DIM];
    __shared__ __align__(16) float sB[C_DIM * M_DIM];
    __shared__ __align__(16) float sPi[C_DIM];
    __shared__ __align__(16) unsigned char xs[2048];
    __shared__ float buf0[C_DIM * 256];   // L8 betas (SoA stride 256)
    __shared__ float buf1[C_DIM * 128];
    __shared__ float wsum[4];

    // ---- per-block staging: tree symbols (coalesced; 16 blocks/tree hit L2) ----
    {
        const int base = t * N1;
        for (int i = tid; i < N1; i += 256)
            xs[i] = (unsigned char)x[inv_map[base + i]];
    }
    // ---- per-block param softmax for this g ----
    {   // A: softmax over i (axis 0) within 16-lane segments; one (i,j)/thread
        int j = tid >> 4, i = tid & 15;
        float v = lA[(i * C_DIM + j) * G_DIM + g];
        float mx = v;
        #pragma unroll
        for (int m = 1; m < 16; m <<= 1) mx = fmaxf(mx, __shfl_xor(mx, m, 16));
        float e = __expf(v - mx);
        float s = e;
        #pragma unroll
        for (int m = 1; m < 16; m <<= 1) s += __shfl_xor(s, m, 16);
        sA[i * C_DIM + j] = e / s;
    }
    {   // B: softmax over m (axis 1), row c, 4 symbols per lane
        int c = tid >> 4, l16 = tid & 15;
        float e0 = lB[(c * M_DIM + l16 +  0) * G_DIM + g];
        float e1 = lB[(c * M_DIM + l16 + 16) * G_DIM + g];
        float e2 = lB[(c * M_DIM + l16 + 32) * G_DIM + g];
        float e3 = lB[(c * M_DIM + l16 + 48) * G_DIM + g];
        float mx = fmaxf(fmaxf(e0, e1), fmaxf(e2, e3));
        #pragma unroll
        for (int m = 1; m < 16; m <<= 1) mx = fmaxf(mx, __shfl_xor(mx, m, 16));
        e0 = __expf(e0 - mx); e1 = __expf(e1 - mx);
        e2 = __expf(e2 - mx); e3 = __expf(e3 - mx);
        float s = e0 + e1 + e2 + e3;
        #pragma unroll
        for (int m = 1; m < 16; m <<= 1) s += __shfl_xor(s, m, 16);
        float inv = 1.f / s;
        sB[c * M_DIM + l16 +  0] = e0 * inv;
        sB[c * M_DIM + l16 + 16] = e1 * inv;
        sB[c * M_DIM + l16 + 32] = e2 * inv;
        sB[c * M_DIM + l16 + 48] = e3 * inv;
    }
    if (tid < C_DIM) {  // Pi: softmax over c across lanes 0..15
        float v = lPi[tid * G_DIM + g];
        float mx = v;
        #pragma unroll
        for (int m = 1; m < 16; m <<= 1) mx = fmaxf(mx, __shfl_xor(mx, m, 16));
        float e = __expf(v - mx);
        float s = e;
        #pragma unroll
        for (int m = 1; m < 16; m <<= 1) s += __shfl_xor(s, m, 16);
        sPi[tid] = e / s;
    }
    __syncthreads();

    float ll = 0.f;

    // ---- fused leaves (L10) + L9 + L8: one L8 node per thread ----
    {
        const int idx = tid;
        const int p8  = 255 + idx;
        float s8[C_DIM];
        #pragma unroll
        for (int k = 0; k < C_DIM; ++k) s8[k] = 0.f;
        #pragma unroll
        for (int c9 = 0; c9 < 2; ++c9) {
            const int p9 = 2 * p8 + 1 + c9;
            float s9[C_DIM];
            #pragma unroll
            for (int k = 0; k < C_DIM; ++k) s9[k] = 0.f;
            #pragma unroll
            for (int cl = 0; cl < 2; ++cl) {
                const int xv = xs[2 * p9 + 1 + cl];
                float b[C_DIM]; float nu = 0.f;
                #pragma unroll
                for (int k = 0; k < C_DIM; ++k) {
                    b[k] = sPi[k] * sB[k * M_DIM + xv];
                    nu += b[k];
                }
                float inv = 0.5f / nu;
                #pragma unroll
                for (int k = 0; k < C_DIM; ++k) s9[k] += b[k] * inv;
                ll += __logf(nu);
            }
            const int xv = xs[p9];
            float bp[C_DIM]; float nu = 0.f;
            #pragma unroll
            for (int i = 0; i < C_DIM; ++i) {
                float ti = 0.f;
                #pragma unroll
                for (int j = 0; j < C_DIM; ++j) ti += sA[i * C_DIM + j] * s9[j];
                bp[i] = ti * sB[i * M_DIM + xv];
                nu += bp[i];
            }
            ll += __logf(nu);
            float inv = 0.5f / nu;
            #pragma unroll
            for (int k = 0; k < C_DIM; ++k) s8[k] += bp[k] * inv;
        }
        const int xv = xs[p8];
        float bp[C_DIM]; float nu = 0.f;
        #pragma unroll
        for (int i = 0; i < C_DIM; ++i) {
            float ti = 0.f;
            #pragma unroll
            for (int j = 0; j < C_DIM; ++j) ti += sA[i * C_DIM + j] * s8[j];
            bp[i] = ti * sB[i * M_DIM + xv];
            nu += bp[i];
        }
        ll += __logf(nu);
        float inv = 1.f / nu;
        #pragma unroll
        for (int k = 0; k < C_DIM; ++k) buf0[k * 256 + idx] = bp[k] * inv;
    }
    __syncthreads();

    // ---- L7: 128 nodes ----
    if (tid < 128) {
        const int idx = tid;
        float s[C_DIM];
        #pragma unroll
        for (int j = 0; j < C_DIM; ++j) {
            float2 cv = ((const float2*)(buf0 + j * 256))[idx];
            s[j] = 0.5f * (cv.x + cv.y);
        }
        const int xv = xs[127 + idx];
        float bp[C_DIM]; float nu = 0.f;
        #pragma unroll
        for (int i = 0; i < C_DIM; ++i) {
            float ti = 0.f;
            #pragma unroll
            for (int j = 0; j < C_DIM; ++j) ti += sA[i * C_DIM + j] * s[j];
            bp[i] = ti * sB[i * M_DIM + xv];
            nu += bp[i];
        }
        ll += __logf(nu);
        float inv = 1.f / nu;
        #pragma unroll
        for (int i = 0; i < C_DIM; ++i) buf1[i * 128 + idx] = bp[i] * inv;
    }
    __syncthreads();

    // ---- L6..L0 (64..1 nodes): wave 0 only, LDS fences not barriers ----
    if (tid < 64) {
        float* cur = buf1; int cs = 128;
        float* nxt = buf0; int ns = 256;
        for (int cnt2 = 64; cnt2 >= 1; cnt2 >>= 1) {
            if (tid < cnt2) {
                const int idx = tid;
                float s[C_DIM];
                #pragma unroll
                for (int j = 0; j < C_DIM; ++j) {
                    float a  = cur[j * cs + 2 * idx];
                    float b2 = cur[j * cs + 2 * idx + 1];
                    s[j] = 0.5f * (a + b2);
                }
                const int xv = xs[cnt2 - 1 + idx];
                float bp[C_DIM]; float nu = 0.f;
                #pragma unroll
                for (int i = 0; i < C_DIM; ++i) {
                    float ti = 0.f;
                    #pragma unroll
                    for (int j = 0; j < C_DIM; ++j) ti += sA[i * C_DIM + j] * s[j];
                    bp[i] = ti * sB[i * M_DIM + xv];
                    nu += bp[i];
                }
                ll += __logf(nu);
                float inv = 1.f / nu;
                #pragma unroll
                for (int i = 0; i < C_DIM; ++i) nxt[i * ns + idx] = bp[i] * inv;
            }
            asm volatile("s_waitcnt lgkmcnt(0)" ::: "memory");
            __builtin_amdgcn_wave_barrier();
            float* tp = cur; cur = nxt; nxt = tp;
            int ts = cs; cs = ns; ns = ts;
        }
    }

    // ---- reduce ll across block ----
    float v = ll;
    #pragma unroll
    for (int off = 32; off > 0; off >>= 1) v += __shfl_down(v, off, 64);
    if ((tid & 63) == 0) wsum[tid >> 6] = v;
    __syncthreads();
    if (tid == 0) out[t * G_DIM + g] = wsum[0] + wsum[1] + wsum[2] + wsum[3];
}

extern "C" void kernel_launch(void* const* d_in, const int* in_sizes, int n_in,
                              void* d_out, int out_size, void* d_ws, size_t ws_size,
                              hipStream_t stream) {
    const int*   x       = (const int*)d_in[0];
    const int*   inv_map = (const int*)d_in[6];
    const float* lA      = (const float*)d_in[7];
    const float* lB      = (const float*)d_in[8];
    const float* lPi     = (const float*)d_in[9];
    float* out = (float*)d_out;

    htmm_fused<<<dim3(NBLOCKS), dim3(256), 0, stream>>>(
        x, inv_map, lA, lB, lPi, out);
}